// Round 5
// baseline (429.338 us; speedup 1.0000x reference)
//
#include <hip/hip_runtime.h>

#define EMB 128

typedef __attribute__((ext_vector_type(8))) short short8;
typedef __attribute__((ext_vector_type(4))) float floatx4;

#define MFMA(a, b, c) __builtin_amdgcn_mfma_f32_16x16x32_bf16((a), (b), (c), 0, 0, 0)

__device__ __forceinline__ ushort f2b(float f) {
    unsigned u = __float_as_uint(f);
    return (ushort)((u + 0x7fff + ((u >> 16) & 1)) >> 16);   // RNE
}
__device__ __forceinline__ float b2f(ushort h) {
    return __uint_as_float(((unsigned)h) << 16);
}
__device__ __forceinline__ short8 cvt8(const float* p) {
    float4 f0 = *(const float4*)p;
    float4 f1 = *(const float4*)(p + 4);
    short8 v;
    v[0] = f2b(f0.x); v[1] = f2b(f0.y); v[2] = f2b(f0.z); v[3] = f2b(f0.w);
    v[4] = f2b(f1.x); v[5] = f2b(f1.y); v[6] = f2b(f1.z); v[7] = f2b(f1.w);
    return v;
}

// ---------------------------------------------------------------------------
// all 5 weight matrices fp32 -> bf16 into one contiguous buffer (one launch)
__global__ void k_cvt_all(const float* __restrict__ w0, const float* __restrict__ w1,
                          const float* __restrict__ w2, const float* __restrict__ w3,
                          const float* __restrict__ w4, ushort* __restrict__ dst) {
    int i = blockIdx.x * blockDim.x + threadIdx.x;   // 0..98303
    const float* src; int off;
    if (i < 16384)      { src = w0; off = i; }
    else if (i < 32768) { src = w1; off = i - 16384; }
    else if (i < 49152) { src = w2; off = i - 32768; }
    else if (i < 81920) { src = w3; off = i - 49152; }
    else                { src = w4; off = i - 81920; }
    dst[i] = f2b(src[off]);
}

// ---------------------------------------------------------------------------
// left projection only: Pl[bf16] = left @ Wl^T + b_left.
// 64 rows/block; wave owns 32 rows x 64 cols; each B-frag feeds 2 MFMAs.
__global__ __launch_bounds__(256) void k_proj_left(const float* __restrict__ X,
                                                   const ushort* __restrict__ Wb,
                                                   const float* __restrict__ bias,
                                                   ushort* __restrict__ Y, int n) {
    int t = threadIdx.x, wave = t >> 6, lane = t & 63;
    int m = lane & 15, quad = lane >> 4;
    int rp = (wave & 1) * 32, colg = (wave >> 1) * 64;
    size_t row0 = (size_t)blockIdx.x * 64;

    short8 a[2][4];
#pragma unroll
    for (int rt = 0; rt < 2; rt++) {
        size_t row = row0 + rp + rt * 16 + m;
        if (row > (size_t)(n - 1)) row = (size_t)(n - 1);
        const float* xr = X + row * EMB;
#pragma unroll
        for (int ks = 0; ks < 4; ks++)
            a[rt][ks] = cvt8(xr + ks * 32 + quad * 8);
    }
#pragma unroll
    for (int ct = 0; ct < 4; ct++) {
        int col = colg + ct * 16 + m;
        floatx4 acc0 = {0.f, 0.f, 0.f, 0.f}, acc1 = {0.f, 0.f, 0.f, 0.f};
#pragma unroll
        for (int ks = 0; ks < 4; ks++) {
            short8 b = *(const short8*)(Wb + (size_t)col * EMB + ks * 32 + quad * 8);
            acc0 = MFMA(a[0][ks], b, acc0);
            acc1 = MFMA(a[1][ks], b, acc1);
        }
        float bb = bias[col];
        size_t r0 = row0 + rp + quad * 4;
#pragma unroll
        for (int r = 0; r < 4; r++) {
            size_t row = r0 + r;
            if (row < (size_t)n) Y[row * EMB + col] = f2b(acc0[r] + bb);
            row += 16;
            if (row < (size_t)n) Y[row * EMB + col] = f2b(acc1[r] + bb);
        }
    }
}

// ---------------------------------------------------------------------------
// counting sort of edges by right index
__global__ void k_hist(const int* __restrict__ eidx, int* __restrict__ cnt,
                       int n_edges) {
    int e = blockIdx.x * blockDim.x + threadIdx.x;
    if (e < n_edges) atomicAdd(&cnt[eidx[n_edges + e]], 1);
}

#define SCAN_CHUNK 4096
__global__ __launch_bounds__(1024) void k_scan1(const int* __restrict__ cnt,
                                                int* __restrict__ offs,
                                                int* __restrict__ bsum, int n) {
    __shared__ int buf[1024];
    int t = threadIdx.x;
    int i0 = blockIdx.x * SCAN_CHUNK + t * 4;
    int v[4];
#pragma unroll
    for (int u = 0; u < 4; u++) { int i = i0 + u; v[u] = (i < n) ? cnt[i] : 0; }
    int s = v[0] + v[1] + v[2] + v[3];
    buf[t] = s;
    __syncthreads();
    for (int d = 1; d < 1024; d <<= 1) {
        int x = (t >= d) ? buf[t - d] : 0;
        __syncthreads();
        buf[t] += x;
        __syncthreads();
    }
    int excl = buf[t] - s;
#pragma unroll
    for (int u = 0; u < 4; u++) { int i = i0 + u; if (i < n) offs[i] = excl; excl += v[u]; }
    if (t == 1023) bsum[blockIdx.x] = buf[1023];
}

__global__ __launch_bounds__(1024) void k_scan2(const int* __restrict__ bsum,
                                                int* __restrict__ offs,
                                                int* __restrict__ cursor, int n) {
    int bid = blockIdx.x;
    int base = 0;
    for (int j = 0; j < bid; j++) base += bsum[j];
    int i0 = bid * SCAN_CHUNK + threadIdx.x * 4;
#pragma unroll
    for (int u = 0; u < 4; u++) {
        int i = i0 + u;
        if (i < n) { int o = offs[i] + base; offs[i] = o; cursor[i] = o; }
    }
}

// emit edges sorted by right index as (left_idx, edge_feat) pairs
__global__ void k_perm(const int* __restrict__ eidx, const float* __restrict__ ef,
                       int* __restrict__ cursor, int2* __restrict__ sle,
                       int n_edges) {
    int e = blockIdx.x * blockDim.x + threadIdx.x;
    if (e < n_edges) {
        int r = eidx[n_edges + e];
        int p = atomicAdd(&cursor[r], 1);
        int2 v; v.x = eidx[e]; v.y = __float_as_int(ef[e]);
        sle[p] = v;
    }
}

// ---------------------------------------------------------------------------
// FUSED: per block of 64 right nodes:
//  A) Pr tile = right @ Wr^T (MFMA) -> LDS            (no global Pr!)
//  B) wave-per-node segmented reduce over sorted edges -> S tile in LDS
//  C) conv = (S@Wf^T + deg*bf)*sp; hidden = relu([conv;right]@W1^T+b1);
//     out = hidden@W2^T + b2.
// The `right` A-fragments are loaded ONCE (used in phase A and phase C-2).
__global__ __launch_bounds__(256) void k_fused(const float* __restrict__ right,
                                               const ushort* __restrict__ Wrb,
                                               const ushort* __restrict__ Pl,
                                               const int2* __restrict__ sle,
                                               const float* __restrict__ We,
                                               const int* __restrict__ offs,
                                               const float* __restrict__ sc_fin,
                                               const ushort* __restrict__ Wfb,
                                               const float* __restrict__ bf,
                                               const float* __restrict__ sc_post,
                                               const ushort* __restrict__ W1b,
                                               const float* __restrict__ b1,
                                               const ushort* __restrict__ W2b,
                                               const float* __restrict__ b2,
                                               float* __restrict__ out,
                                               int n, int n_edges) {
    __shared__ ushort PRT[64][136];   // Pr tile; reused as T (hidden) in phase C
    __shared__ ushort SS[64][136];    // S tile
    __shared__ ushort H[64][136];     // conv tile
    __shared__ float degs[64];

    int t = threadIdx.x, wave = t >> 6, lane = t & 63;
    int m = lane & 15, quad = lane >> 4;
    int rp = (wave & 1) * 32, colg = (wave >> 1) * 64;
    size_t row0 = (size_t)blockIdx.x * 64;
    float scale = sc_fin[0];
    float sp = sc_post[0];

    if (t < 64) {
        size_t rr = row0 + t;
        if (rr < (size_t)n) {
            int s0 = offs[rr];
            int s1 = (rr + 1 < (size_t)n) ? offs[rr + 1] : n_edges;
            degs[t] = (float)(s1 - s0);
        } else degs[t] = 0.f;
    }

    // A-fragments of `right` (shared by phase A and phase C-2)
    short8 ar[2][4];
#pragma unroll
    for (int rt = 0; rt < 2; rt++) {
        size_t row = row0 + rp + rt * 16 + m;
        if (row > (size_t)(n - 1)) row = (size_t)(n - 1);
        const float* rr = right + row * EMB;
#pragma unroll
        for (int ks = 0; ks < 4; ks++)
            ar[rt][ks] = cvt8(rr + ks * 32 + quad * 8);
    }

    // ---- phase A: Pr tile -> PRT ----
#pragma unroll
    for (int ct = 0; ct < 4; ct++) {
        int col = colg + ct * 16 + m;
        floatx4 acc0 = {0.f, 0.f, 0.f, 0.f}, acc1 = {0.f, 0.f, 0.f, 0.f};
#pragma unroll
        for (int ks = 0; ks < 4; ks++) {
            short8 b = *(const short8*)(Wrb + (size_t)col * EMB + ks * 32 + quad * 8);
            acc0 = MFMA(ar[0][ks], b, acc0);
            acc1 = MFMA(ar[1][ks], b, acc1);
        }
        int r0 = rp + quad * 4;
#pragma unroll
        for (int r = 0; r < 4; r++) {
            PRT[r0 + r][col]      = f2b(acc0[r]);
            PRT[r0 + 16 + r][col] = f2b(acc1[r]);
        }
    }
    __syncthreads();

    // ---- phase B: segmented reduce; wave handles 16 contiguous nodes ----
    float2 we = *(const float2*)(We + lane * 2);
    for (int i = 0; i < 16; i++) {
        int node = wave * 16 + i;
        size_t grow = row0 + node;
        float ax = 0.f, ay = 0.f;
        if (grow < (size_t)n) {
            int s0 = offs[grow];
            int s1 = (grow + 1 < (size_t)n) ? offs[grow + 1] : n_edges;
            ushort2 pru = *(const ushort2*)&PRT[node][lane * 2];
            float prx = b2f(pru.x), pry = b2f(pru.y);
            int ei = s0;
            for (; ei + 4 <= s1; ei += 4) {
                int2 e0 = sle[ei], e1 = sle[ei + 1], e2 = sle[ei + 2], e3 = sle[ei + 3];
                ushort2 p0 = *(const ushort2*)(Pl + (size_t)e0.x * EMB + lane * 2);
                ushort2 p1 = *(const ushort2*)(Pl + (size_t)e1.x * EMB + lane * 2);
                ushort2 p2 = *(const ushort2*)(Pl + (size_t)e2.x * EMB + lane * 2);
                ushort2 p3 = *(const ushort2*)(Pl + (size_t)e3.x * EMB + lane * 2);
                float f0 = __int_as_float(e0.y), f1 = __int_as_float(e1.y);
                float f2_ = __int_as_float(e2.y), f3 = __int_as_float(e3.y);
                ax += fmaxf((b2f(p0.x) + prx + f0 * we.x) * scale, 0.f);
                ay += fmaxf((b2f(p0.y) + pry + f0 * we.y) * scale, 0.f);
                ax += fmaxf((b2f(p1.x) + prx + f1 * we.x) * scale, 0.f);
                ay += fmaxf((b2f(p1.y) + pry + f1 * we.y) * scale, 0.f);
                ax += fmaxf((b2f(p2.x) + prx + f2_ * we.x) * scale, 0.f);
                ay += fmaxf((b2f(p2.y) + pry + f2_ * we.y) * scale, 0.f);
                ax += fmaxf((b2f(p3.x) + prx + f3 * we.x) * scale, 0.f);
                ay += fmaxf((b2f(p3.y) + pry + f3 * we.y) * scale, 0.f);
            }
            for (; ei < s1; ei++) {
                int2 e0 = sle[ei];
                ushort2 p0 = *(const ushort2*)(Pl + (size_t)e0.x * EMB + lane * 2);
                float f0 = __int_as_float(e0.y);
                ax += fmaxf((b2f(p0.x) + prx + f0 * we.x) * scale, 0.f);
                ay += fmaxf((b2f(p0.y) + pry + f0 * we.y) * scale, 0.f);
            }
        }
        ushort2 o; o.x = f2b(ax); o.y = f2b(ay);
        *(ushort2*)&SS[node][lane * 2] = o;
    }
    __syncthreads();

    // ---- phase C-1: conv = (S @ Wf^T + deg*bf) * sp -> H ----
    short8 a1[2][4];
#pragma unroll
    for (int rt = 0; rt < 2; rt++)
#pragma unroll
        for (int ks = 0; ks < 4; ks++)
            a1[rt][ks] = *(const short8*)(&SS[rp + rt * 16 + m][ks * 32 + quad * 8]);
#pragma unroll
    for (int ct = 0; ct < 4; ct++) {
        int col = colg + ct * 16 + m;
        floatx4 acc0 = {0.f, 0.f, 0.f, 0.f}, acc1 = {0.f, 0.f, 0.f, 0.f};
#pragma unroll
        for (int ks = 0; ks < 4; ks++) {
            short8 b = *(const short8*)(Wfb + (size_t)col * EMB + ks * 32 + quad * 8);
            acc0 = MFMA(a1[0][ks], b, acc0);
            acc1 = MFMA(a1[1][ks], b, acc1);
        }
        float bb = bf[col];
        int r0 = rp + quad * 4;
#pragma unroll
        for (int r = 0; r < 4; r++) {
            H[r0 + r][col]      = f2b((acc0[r] + degs[r0 + r] * bb) * sp);
            H[r0 + 16 + r][col] = f2b((acc1[r] + degs[r0 + 16 + r] * bb) * sp);
        }
    }
    __syncthreads();

    // ---- phase C-2: hidden = relu([H ; ar] @ W1^T + b1) -> PRT (as T) ----
    short8 a2[2][4];
#pragma unroll
    for (int rt = 0; rt < 2; rt++)
#pragma unroll
        for (int ks = 0; ks < 4; ks++)
            a2[rt][ks] = *(const short8*)(&H[rp + rt * 16 + m][ks * 32 + quad * 8]);
#pragma unroll
    for (int ct = 0; ct < 4; ct++) {
        int col = colg + ct * 16 + m;
        floatx4 acc0 = {0.f, 0.f, 0.f, 0.f}, acc1 = {0.f, 0.f, 0.f, 0.f};
        const ushort* wrow = W1b + (size_t)col * 256;
#pragma unroll
        for (int ks = 0; ks < 4; ks++) {
            short8 b = *(const short8*)(wrow + ks * 32 + quad * 8);
            acc0 = MFMA(a2[0][ks], b, acc0);
            acc1 = MFMA(a2[1][ks], b, acc1);
        }
#pragma unroll
        for (int ks = 0; ks < 4; ks++) {
            short8 b = *(const short8*)(wrow + 128 + ks * 32 + quad * 8);
            acc0 = MFMA(ar[0][ks], b, acc0);
            acc1 = MFMA(ar[1][ks], b, acc1);
        }
        float bb = b1[col];
        int r0 = rp + quad * 4;
#pragma unroll
        for (int r = 0; r < 4; r++) {
            PRT[r0 + r][col]      = f2b(fmaxf(acc0[r] + bb, 0.f));
            PRT[r0 + 16 + r][col] = f2b(fmaxf(acc1[r] + bb, 0.f));
        }
    }
    __syncthreads();

    // ---- phase C-3: out = T @ W2^T + b2 ----
    short8 a3[2][4];
#pragma unroll
    for (int rt = 0; rt < 2; rt++)
#pragma unroll
        for (int ks = 0; ks < 4; ks++)
            a3[rt][ks] = *(const short8*)(&PRT[rp + rt * 16 + m][ks * 32 + quad * 8]);
#pragma unroll
    for (int ct = 0; ct < 4; ct++) {
        int col = colg + ct * 16 + m;
        floatx4 acc0 = {0.f, 0.f, 0.f, 0.f}, acc1 = {0.f, 0.f, 0.f, 0.f};
#pragma unroll
        for (int ks = 0; ks < 4; ks++) {
            short8 b = *(const short8*)(W2b + (size_t)col * EMB + ks * 32 + quad * 8);
            acc0 = MFMA(a3[0][ks], b, acc0);
            acc1 = MFMA(a3[1][ks], b, acc1);
        }
        float bb = b2[col];
        size_t r0 = row0 + rp + quad * 4;
#pragma unroll
        for (int r = 0; r < 4; r++) {
            size_t row = r0 + r;
            if (row < (size_t)n) out[row * EMB + col] = acc0[r] + bb;
            row += 16;
            if (row < (size_t)n) out[row * EMB + col] = acc1[r] + bb;
        }
    }
}

// ---------------------------------------------------------------------------
extern "C" void kernel_launch(void* const* d_in, const int* in_sizes, int n_in,
                              void* d_out, int out_size, void* d_ws, size_t ws_size,
                              hipStream_t stream) {
    const float* left   = (const float*)d_in[0];
    const int*   eidx   = (const int*)  d_in[1];
    const float* efeat  = (const float*)d_in[2];
    const float* right  = (const float*)d_in[3];
    const float* W_left = (const float*)d_in[5];
    const float* b_left = (const float*)d_in[6];
    const float* W_edge = (const float*)d_in[7];
    const float* W_right= (const float*)d_in[8];
    const float* sc_fin = (const float*)d_in[9];
    const float* W_fin  = (const float*)d_in[10];
    const float* b_fin  = (const float*)d_in[11];
    const float* sc_post= (const float*)d_in[12];
    const float* W_out1 = (const float*)d_in[13];
    const float* b_out1 = (const float*)d_in[14];
    const float* W_out2 = (const float*)d_in[15];
    const float* b_out2 = (const float*)d_in[16];

    int n_left  = in_sizes[0] / EMB;        // 100000
    int n_edges = in_sizes[2];              // 600000
    int n_right = in_sizes[3] / EMB;        // 100000

    ushort* us = (ushort*)d_ws;
    ushort* Wl_b = us;                       // packed bf16 weight buffer
    ushort* Wr_b = us + 16384;
    ushort* Wf_b = us + 32768;
    ushort* W1_b = us + 49152;
    ushort* W2_b = us + 81920;
    ushort* Pl   = us + 98304;               // n_left*128 bf16
    int* cnt    = (int*)(Pl + (size_t)n_left * EMB);
    int* offs   = cnt + n_right;
    int* cursor = offs + n_right;
    int* bsum   = cursor + n_right;
    int2* sle   = (int2*)(bsum + 64);

    hipMemsetAsync(cnt, 0, (size_t)n_right * sizeof(int), stream);

    // weights -> bf16 (natural row-major; no transposes needed for MFMA B)
    k_cvt_all<<<384, 256, 0, stream>>>(W_left, W_right, W_fin, W_out1, W_out2, us);

    // counting sort of edges by right index
    int eb = (n_edges + 255) / 256;
    k_hist<<<eb, 256, 0, stream>>>(eidx, cnt, n_edges);
    int nsb = (n_right + SCAN_CHUNK - 1) / SCAN_CHUNK;   // 25
    k_scan1<<<nsb, 1024, 0, stream>>>(cnt, offs, bsum, n_right);
    k_scan2<<<nsb, 1024, 0, stream>>>(bsum, offs, cursor, n_right);
    k_perm<<<eb, 256, 0, stream>>>(eidx, efeat, cursor, sle, n_edges);

    // left projection
    k_proj_left<<<(n_left + 63) / 64, 256, 0, stream>>>(left, Wl_b, b_left, Pl, n_left);

    // fused right-proj + segmented reduce + conv GEMM + output MLP
    k_fused<<<(n_right + 63) / 64, 256, 0, stream>>>(right, Wr_b, Pl, sle, W_edge,
                                                     offs, sc_fin, Wf_b, b_fin,
                                                     sc_post, W1_b, b_out1,
                                                     W2_b, b_out2,
                                                     (float*)d_out, n_right, n_edges);
}

// Round 6
// 404.814 us; speedup vs baseline: 1.0606x; 1.0606x over previous
//
#include <hip/hip_runtime.h>

#define EMB 128

typedef __attribute__((ext_vector_type(8))) short short8;
typedef __attribute__((ext_vector_type(4))) float floatx4;

#define MFMA(a, b, c) __builtin_amdgcn_mfma_f32_16x16x32_bf16((a), (b), (c), 0, 0, 0)

__device__ __forceinline__ ushort f2b(float f) {
    unsigned u = __float_as_uint(f);
    return (ushort)((u + 0x7fff + ((u >> 16) & 1)) >> 16);   // RNE
}
__device__ __forceinline__ float b2f(ushort h) {
    return __uint_as_float(((unsigned)h) << 16);
}
__device__ __forceinline__ short8 cvt8(const float* p) {
    float4 f0 = *(const float4*)p;
    float4 f1 = *(const float4*)(p + 4);
    short8 v;
    v[0] = f2b(f0.x); v[1] = f2b(f0.y); v[2] = f2b(f0.z); v[3] = f2b(f0.w);
    v[4] = f2b(f1.x); v[5] = f2b(f1.y); v[6] = f2b(f1.z); v[7] = f2b(f1.w);
    return v;
}

// ---------------------------------------------------------------------------
// fused independent pre-work: blocks [0,384) convert the 5 weight matrices to
// bf16; blocks [384, 384+eb) histogram right indices.
__global__ __launch_bounds__(256) void k_cvthist(const float* __restrict__ w0,
                                                 const float* __restrict__ w1,
                                                 const float* __restrict__ w2,
                                                 const float* __restrict__ w3,
                                                 const float* __restrict__ w4,
                                                 ushort* __restrict__ dst,
                                                 const int* __restrict__ eidx,
                                                 int* __restrict__ cnt,
                                                 int n_edges) {
    int bid = blockIdx.x;
    if (bid < 384) {
        int i = bid * 256 + threadIdx.x;     // 0..98303
        const float* src; int off;
        if (i < 16384)      { src = w0; off = i; }
        else if (i < 32768) { src = w1; off = i - 16384; }
        else if (i < 49152) { src = w2; off = i - 32768; }
        else if (i < 81920) { src = w3; off = i - 49152; }
        else                { src = w4; off = i - 81920; }
        dst[i] = f2b(src[off]);
    } else {
        int e = (bid - 384) * 256 + threadIdx.x;
        if (e < n_edges) atomicAdd(&cnt[eidx[n_edges + e]], 1);
    }
}

#define SCAN_CHUNK 4096
__global__ __launch_bounds__(1024) void k_scan1(const int* __restrict__ cnt,
                                                int* __restrict__ offs,
                                                int* __restrict__ bsum, int n) {
    __shared__ int buf[1024];
    int t = threadIdx.x;
    int i0 = blockIdx.x * SCAN_CHUNK + t * 4;
    int v[4];
#pragma unroll
    for (int u = 0; u < 4; u++) { int i = i0 + u; v[u] = (i < n) ? cnt[i] : 0; }
    int s = v[0] + v[1] + v[2] + v[3];
    buf[t] = s;
    __syncthreads();
    for (int d = 1; d < 1024; d <<= 1) {
        int x = (t >= d) ? buf[t - d] : 0;
        __syncthreads();
        buf[t] += x;
        __syncthreads();
    }
    int excl = buf[t] - s;
#pragma unroll
    for (int u = 0; u < 4; u++) { int i = i0 + u; if (i < n) offs[i] = excl; excl += v[u]; }
    if (t == 1023) bsum[blockIdx.x] = buf[1023];
}

__global__ __launch_bounds__(1024) void k_scan2(const int* __restrict__ bsum,
                                                int* __restrict__ offs,
                                                int* __restrict__ cursor, int n) {
    int bid = blockIdx.x;
    int base = 0;
    for (int j = 0; j < bid; j++) base += bsum[j];
    int i0 = bid * SCAN_CHUNK + threadIdx.x * 4;
#pragma unroll
    for (int u = 0; u < 4; u++) {
        int i = i0 + u;
        if (i < n) { int o = offs[i] + base; offs[i] = o; cursor[i] = o; }
    }
}

// ---------------------------------------------------------------------------
// fused: blocks [0,eb) -> perm (sorted (li,ef) list); [eb, eb+nblk) -> left
// projection; [eb+nblk, eb+2*nblk) -> right projection.
__global__ __launch_bounds__(256) void k_permproj(const int* __restrict__ eidx,
                                                  const float* __restrict__ ef,
                                                  int* __restrict__ cursor,
                                                  int2* __restrict__ sle,
                                                  int n_edges,
                                                  const float* __restrict__ XL,
                                                  const float* __restrict__ XR,
                                                  const ushort* __restrict__ WLb,
                                                  const ushort* __restrict__ WRb,
                                                  const float* __restrict__ bias,
                                                  ushort* __restrict__ YL,
                                                  ushort* __restrict__ YR,
                                                  int n, int eb, int nblk) {
    int bid = blockIdx.x;
    if (bid < eb) {
        int e = bid * 256 + threadIdx.x;
        if (e < n_edges) {
            int r = eidx[n_edges + e];
            int p = atomicAdd(&cursor[r], 1);
            int2 v; v.x = eidx[e]; v.y = __float_as_int(ef[e]);
            sle[p] = v;
        }
        return;
    }
    bid -= eb;
    const float* X; const ushort* Wb; ushort* Y; int has_bias;
    if (bid < nblk) { X = XL; Wb = WLb; Y = YL; has_bias = 1; }
    else            { X = XR; Wb = WRb; Y = YR; has_bias = 0; bid -= nblk; }

    int t = threadIdx.x, wave = t >> 6, lane = t & 63;
    int m = lane & 15, quad = lane >> 4;
    int rp = (wave & 1) * 32, colg = (wave >> 1) * 64;
    size_t row0 = (size_t)bid * 64;

    short8 a[2][4];
#pragma unroll
    for (int rt = 0; rt < 2; rt++) {
        size_t row = row0 + rp + rt * 16 + m;
        if (row > (size_t)(n - 1)) row = (size_t)(n - 1);
        const float* xr = X + row * EMB;
#pragma unroll
        for (int ks = 0; ks < 4; ks++)
            a[rt][ks] = cvt8(xr + ks * 32 + quad * 8);
    }
#pragma unroll
    for (int ct = 0; ct < 4; ct++) {
        int col = colg + ct * 16 + m;
        floatx4 acc0 = {0.f, 0.f, 0.f, 0.f}, acc1 = {0.f, 0.f, 0.f, 0.f};
#pragma unroll
        for (int ks = 0; ks < 4; ks++) {
            short8 b = *(const short8*)(Wb + (size_t)col * EMB + ks * 32 + quad * 8);
            acc0 = MFMA(a[0][ks], b, acc0);
            acc1 = MFMA(a[1][ks], b, acc1);
        }
        float bb = has_bias ? bias[col] : 0.f;
        size_t r0 = row0 + rp + quad * 4;
#pragma unroll
        for (int r = 0; r < 4; r++) {
            size_t row = r0 + r;
            if (row < (size_t)n) Y[row * EMB + col] = f2b(acc0[r] + bb);
            row += 16;
            if (row < (size_t)n) Y[row * EMB + col] = f2b(acc1[r] + bb);
        }
    }
}

// ---------------------------------------------------------------------------
// segmented reduction: S[r] = sum_e relu(scale*(Pl[l]+Pr[r]+ef*We)), bf16 out.
// one wave per right node; sorted single-indirection list; unroll x4 MLP.
__global__ __launch_bounds__(256) void k_reduce(const ushort* __restrict__ Pl,
                                                const ushort* __restrict__ Pr,
                                                const int2* __restrict__ sle,
                                                const float* __restrict__ We,
                                                const int* __restrict__ offs,
                                                const float* __restrict__ scale_final,
                                                ushort* __restrict__ S,
                                                int n_right, int n_edges) {
    int r = blockIdx.x * 4 + (threadIdx.x >> 6);
    int lane = threadIdx.x & 63;
    float scale = scale_final[0];
    float2 we = *(const float2*)(We + lane * 2);
    ushort2 pru = *(const ushort2*)(Pr + (size_t)r * EMB + lane * 2);
    float prx = b2f(pru.x), pry = b2f(pru.y);
    float ax = 0.f, ay = 0.f;
    int s0 = offs[r];
    int s1 = (r + 1 < n_right) ? offs[r + 1] : n_edges;
    int ei = s0;
    for (; ei + 4 <= s1; ei += 4) {
        int2 e0 = sle[ei], e1 = sle[ei + 1], e2 = sle[ei + 2], e3 = sle[ei + 3];
        ushort2 p0 = *(const ushort2*)(Pl + (size_t)e0.x * EMB + lane * 2);
        ushort2 p1 = *(const ushort2*)(Pl + (size_t)e1.x * EMB + lane * 2);
        ushort2 p2 = *(const ushort2*)(Pl + (size_t)e2.x * EMB + lane * 2);
        ushort2 p3 = *(const ushort2*)(Pl + (size_t)e3.x * EMB + lane * 2);
        float f0 = __int_as_float(e0.y), f1 = __int_as_float(e1.y);
        float f2_ = __int_as_float(e2.y), f3 = __int_as_float(e3.y);
        ax += fmaxf((b2f(p0.x) + prx + f0 * we.x) * scale, 0.f);
        ay += fmaxf((b2f(p0.y) + pry + f0 * we.y) * scale, 0.f);
        ax += fmaxf((b2f(p1.x) + prx + f1 * we.x) * scale, 0.f);
        ay += fmaxf((b2f(p1.y) + pry + f1 * we.y) * scale, 0.f);
        ax += fmaxf((b2f(p2.x) + prx + f2_ * we.x) * scale, 0.f);
        ay += fmaxf((b2f(p2.y) + pry + f2_ * we.y) * scale, 0.f);
        ax += fmaxf((b2f(p3.x) + prx + f3 * we.x) * scale, 0.f);
        ay += fmaxf((b2f(p3.y) + pry + f3 * we.y) * scale, 0.f);
    }
    for (; ei < s1; ei++) {
        int2 e0 = sle[ei];
        ushort2 p0 = *(const ushort2*)(Pl + (size_t)e0.x * EMB + lane * 2);
        float f0 = __int_as_float(e0.y);
        ax += fmaxf((b2f(p0.x) + prx + f0 * we.x) * scale, 0.f);
        ay += fmaxf((b2f(p0.y) + pry + f0 * we.y) * scale, 0.f);
    }
    ushort2 o; o.x = f2b(ax); o.y = f2b(ay);
    *(ushort2*)(S + (size_t)r * EMB + lane * 2) = o;
}

// ---------------------------------------------------------------------------
// fused conv GEMM + output MLP.  64 rows/block; wave = 32 rows x 64 cols;
// single LDS tile H reused for conv then hidden (a2 frags are in registers
// across the overwrite, guarded by barriers).  LDS ~17.7 KB -> high occupancy.
__global__ __launch_bounds__(256) void k_out_mfma(const ushort* __restrict__ S,
                                                  const float* __restrict__ right,
                                                  const ushort* __restrict__ Wfb,
                                                  const float* __restrict__ bf,
                                                  const int* __restrict__ deg,
                                                  const float* __restrict__ sc_post,
                                                  const ushort* __restrict__ W1b,
                                                  const float* __restrict__ b1,
                                                  const ushort* __restrict__ W2b,
                                                  const float* __restrict__ b2,
                                                  float* __restrict__ out, int n) {
    __shared__ ushort H[64][136];
    __shared__ float degs[64];
    int t = threadIdx.x, wave = t >> 6, lane = t & 63;
    int m = lane & 15, quad = lane >> 4;
    int rp = (wave & 1) * 32, colg = (wave >> 1) * 64;
    size_t row0 = (size_t)blockIdx.x * 64;
    float sp = sc_post[0];

    if (t < 64) {
        size_t rr = row0 + t;
        degs[t] = (rr < (size_t)n) ? (float)deg[rr] : 0.f;
    }

    // A-fragments: S (conv GEMM) and right (second half of concat GEMM)
    short8 a1[2][4], ar[2][4];
#pragma unroll
    for (int rt = 0; rt < 2; rt++) {
        size_t row = row0 + rp + rt * 16 + m;
        if (row > (size_t)(n - 1)) row = (size_t)(n - 1);
        const ushort* sr = S + row * EMB;
        const float* rr = right + row * EMB;
#pragma unroll
        for (int ks = 0; ks < 4; ks++) {
            a1[rt][ks] = *(const short8*)(sr + ks * 32 + quad * 8);
            ar[rt][ks] = cvt8(rr + ks * 32 + quad * 8);
        }
    }
    __syncthreads();   // degs visible

    // phase 1: conv = (S @ Wf^T + deg*bf) * sp -> H
#pragma unroll
    for (int ct = 0; ct < 4; ct++) {
        int col = colg + ct * 16 + m;
        floatx4 acc0 = {0.f, 0.f, 0.f, 0.f}, acc1 = {0.f, 0.f, 0.f, 0.f};
#pragma unroll
        for (int ks = 0; ks < 4; ks++) {
            short8 b = *(const short8*)(Wfb + (size_t)col * EMB + ks * 32 + quad * 8);
            acc0 = MFMA(a1[0][ks], b, acc0);
            acc1 = MFMA(a1[1][ks], b, acc1);
        }
        float bb = bf[col];
        int r0 = rp + quad * 4;
#pragma unroll
        for (int r = 0; r < 4; r++) {
            H[r0 + r][col]      = f2b((acc0[r] + degs[r0 + r] * bb) * sp);
            H[r0 + 16 + r][col] = f2b((acc1[r] + degs[r0 + 16 + r] * bb) * sp);
        }
    }
    __syncthreads();

    // load conv A-frags, then (barrier) overwrite H with hidden
    short8 a2[2][4];
#pragma unroll
    for (int rt = 0; rt < 2; rt++)
#pragma unroll
        for (int ks = 0; ks < 4; ks++)
            a2[rt][ks] = *(const short8*)(&H[rp + rt * 16 + m][ks * 32 + quad * 8]);
    __syncthreads();   // all conv reads complete before overwrite

    // phase 2: hidden = relu([conv ; right] @ W1^T + b1) -> H
#pragma unroll
    for (int ct = 0; ct < 4; ct++) {
        int col = colg + ct * 16 + m;
        floatx4 acc0 = {0.f, 0.f, 0.f, 0.f}, acc1 = {0.f, 0.f, 0.f, 0.f};
        const ushort* wrow = W1b + (size_t)col * 256;
#pragma unroll
        for (int ks = 0; ks < 4; ks++) {
            short8 b = *(const short8*)(wrow + ks * 32 + quad * 8);
            acc0 = MFMA(a2[0][ks], b, acc0);
            acc1 = MFMA(a2[1][ks], b, acc1);
        }
#pragma unroll
        for (int ks = 0; ks < 4; ks++) {
            short8 b = *(const short8*)(wrow + 128 + ks * 32 + quad * 8);
            acc0 = MFMA(ar[0][ks], b, acc0);
            acc1 = MFMA(ar[1][ks], b, acc1);
        }
        float bb = b1[col];
        int r0 = rp + quad * 4;
#pragma unroll
        for (int r = 0; r < 4; r++) {
            H[r0 + r][col]      = f2b(fmaxf(acc0[r] + bb, 0.f));
            H[r0 + 16 + r][col] = f2b(fmaxf(acc1[r] + bb, 0.f));
        }
    }
    __syncthreads();

    // phase 3: out = hidden @ W2^T + b2
    short8 a3[2][4];
#pragma unroll
    for (int rt = 0; rt < 2; rt++)
#pragma unroll
        for (int ks = 0; ks < 4; ks++)
            a3[rt][ks] = *(const short8*)(&H[rp + rt * 16 + m][ks * 32 + quad * 8]);
#pragma unroll
    for (int ct = 0; ct < 4; ct++) {
        int col = colg + ct * 16 + m;
        floatx4 acc0 = {0.f, 0.f, 0.f, 0.f}, acc1 = {0.f, 0.f, 0.f, 0.f};
#pragma unroll
        for (int ks = 0; ks < 4; ks++) {
            short8 b = *(const short8*)(W2b + (size_t)col * EMB + ks * 32 + quad * 8);
            acc0 = MFMA(a3[0][ks], b, acc0);
            acc1 = MFMA(a3[1][ks], b, acc1);
        }
        float bb = b2[col];
        size_t r0 = row0 + rp + quad * 4;
#pragma unroll
        for (int r = 0; r < 4; r++) {
            size_t row = r0 + r;
            if (row < (size_t)n) out[row * EMB + col] = acc0[r] + bb;
            row += 16;
            if (row < (size_t)n) out[row * EMB + col] = acc1[r] + bb;
        }
    }
}

// ---------------------------------------------------------------------------
extern "C" void kernel_launch(void* const* d_in, const int* in_sizes, int n_in,
                              void* d_out, int out_size, void* d_ws, size_t ws_size,
                              hipStream_t stream) {
    const float* left   = (const float*)d_in[0];
    const int*   eidx   = (const int*)  d_in[1];
    const float* efeat  = (const float*)d_in[2];
    const float* right  = (const float*)d_in[3];
    const float* W_left = (const float*)d_in[5];
    const float* b_left = (const float*)d_in[6];
    const float* W_edge = (const float*)d_in[7];
    const float* W_right= (const float*)d_in[8];
    const float* sc_fin = (const float*)d_in[9];
    const float* W_fin  = (const float*)d_in[10];
    const float* b_fin  = (const float*)d_in[11];
    const float* sc_post= (const float*)d_in[12];
    const float* W_out1 = (const float*)d_in[13];
    const float* b_out1 = (const float*)d_in[14];
    const float* W_out2 = (const float*)d_in[15];
    const float* b_out2 = (const float*)d_in[16];

    int n_left  = in_sizes[0] / EMB;        // 100000
    int n_edges = in_sizes[2];              // 600000
    int n_right = in_sizes[3] / EMB;        // 100000

    ushort* us = (ushort*)d_ws;
    ushort* Wl_b = us;                       // packed bf16 weights
    ushort* Wr_b = us + 16384;
    ushort* Wf_b = us + 32768;
    ushort* W1_b = us + 49152;
    ushort* W2_b = us + 81920;
    ushort* Pl   = us + 98304;               // n_left*128
    ushort* Pr   = Pl + (size_t)n_left * EMB;
    ushort* S    = Pr + (size_t)n_right * EMB;
    int* cnt    = (int*)(S + (size_t)n_right * EMB);
    int* offs   = cnt + n_right;
    int* cursor = offs + n_right;
    int* bsum   = cursor + n_right;
    int2* sle   = (int2*)(bsum + 64);

    hipMemsetAsync(cnt, 0, (size_t)n_right * sizeof(int), stream);

    int eb = (n_edges + 255) / 256;          // 2344
    int nblk = (n_left + 63) / 64;           // 1563

    // weights->bf16 + degree histogram (independent, one launch)
    k_cvthist<<<384 + eb, 256, 0, stream>>>(W_left, W_right, W_fin, W_out1,
                                            W_out2, us, eidx, cnt, n_edges);

    // exclusive scan of degrees
    int nsb = (n_right + SCAN_CHUNK - 1) / SCAN_CHUNK;   // 25
    k_scan1<<<nsb, 1024, 0, stream>>>(cnt, offs, bsum, n_right);
    k_scan2<<<nsb, 1024, 0, stream>>>(bsum, offs, cursor, n_right);

    // sorted edge list + both projections (independent, one launch)
    k_permproj<<<eb + 2 * nblk, 256, 0, stream>>>(eidx, efeat, cursor, sle,
                                                  n_edges, left, right,
                                                  Wl_b, Wr_b, b_left,
                                                  Pl, Pr, n_left, eb, nblk);

    // segmented reduction -> S
    k_reduce<<<n_right / 4, 256, 0, stream>>>(Pl, Pr, sle, W_edge, offs,
                                              sc_fin, S, n_right, n_edges);

    // fused conv GEMM + output MLP
    k_out_mfma<<<(n_right + 63) / 64, 256, 0, stream>>>(S, right, Wf_b, b_fin,
                                                        cnt, sc_post, W1_b, b_out1,
                                                        W2_b, b_out2,
                                                        (float*)d_out, n_right);
}